// Round 20
// baseline (296.289 us; speedup 1.0000x reference)
//
#include <hip/hip_runtime.h>
#include <hip/hip_bf16.h>

typedef __hip_bfloat16 bf16;
typedef short bf16x8 __attribute__((ext_vector_type(8)));
typedef float f32x4 __attribute__((ext_vector_type(4)));

#define MFMA16(a, b, c) __builtin_amdgcn_mfma_f32_16x16x32_bf16((a), (b), (c), 0, 0, 0)

__device__ __forceinline__ short f2bs(float f) {
  bf16 h = __float2bfloat16(f);
  return __builtin_bit_cast(short, h);
}
__device__ __forceinline__ float bs2f(short s) {
  return __bfloat162float(__builtin_bit_cast(bf16, s));
}

// async global->LDS, 16B per lane; LDS dest = wave-uniform base + lane*16
__device__ __forceinline__ void gload16(const void* g, const void* l) {
  __builtin_amdgcn_global_load_lds(
      (const __attribute__((address_space(1))) unsigned int*)g,
      (__attribute__((address_space(3))) unsigned int*)l, 16, 0, 0);
}

// ---------------------------------------------------------------------------
// f32->bf16 transpose core: dst[N][K](bf16) = src[K][N](f32)^T, 64x64 tile.
// ---------------------------------------------------------------------------
__device__ __forceinline__ void t_cvt_core(const float* __restrict__ src,
                                           bf16* __restrict__ dst, int K, int N,
                                           int bx, int by, short Ts[64][72]) {
  const long n0 = (long)bx * 64, k0 = (long)by * 64;
  const int r = threadIdx.x >> 2, c4 = threadIdx.x & 3;
  const float* s = src + (k0 + r) * (long)N + n0 + c4 * 16;
  #pragma unroll
  for (int j = 0; j < 4; ++j) {
    float4 v = *(const float4*)(s + j * 4);
    Ts[r][c4 * 16 + j * 4 + 0] = f2bs(v.x);
    Ts[r][c4 * 16 + j * 4 + 1] = f2bs(v.y);
    Ts[r][c4 * 16 + j * 4 + 2] = f2bs(v.z);
    Ts[r][c4 * 16 + j * 4 + 3] = f2bs(v.w);
  }
  __syncthreads();
  union { uint4 v; short sh[8]; } o0, o1;
  #pragma unroll
  for (int j = 0; j < 8; ++j) o0.sh[j] = Ts[c4 * 16 + j][r];
  #pragma unroll
  for (int j = 0; j < 8; ++j) o1.sh[j] = Ts[c4 * 16 + 8 + j][r];
  *(uint4*)(dst + (n0 + r) * (long)K + k0 + c4 * 16)     = o0.v;
  *(uint4*)(dst + (n0 + r) * (long)K + k0 + c4 * 16 + 8) = o1.v;
}

// ---------------------------------------------------------------------------
// mega-prep: flat cvt (hs, q_ln, kv_ln) + ALL five weight transposes. 7841 blk.
// ---------------------------------------------------------------------------
__global__ __launch_bounds__(256) void prep_all(
    const float* __restrict__ hs_f, bf16* __restrict__ hs_c,
    const float* __restrict__ qln_f, bf16* __restrict__ qln_c,
    const float* __restrict__ kvln_f, bf16* __restrict__ kvln_c,
    const float* __restrict__ Wqa_f, bf16* __restrict__ wqaT,
    const float* __restrict__ Wkva_f, bf16* __restrict__ wkvaT,
    const float* __restrict__ Wqb_f, bf16* __restrict__ wqbT,
    const float* __restrict__ Wkvb_f, bf16* __restrict__ wkvbT,
    const float* __restrict__ Wo_f, bf16* __restrict__ woT)
{
  __shared__ __align__(16) short Ts[64][72];
  const int bid = blockIdx.x;
  if (bid < 4097) {
    int i = bid * 256 + threadIdx.x;
    const float* s; bf16* d; int idx;
    if (i < 1048576)            { s = hs_f;   d = hs_c;   idx = i; }
    else if (i < 1048576 + 192) { s = qln_f;  d = qln_c;  idx = i - 1048576; }
    else                        { s = kvln_f; d = kvln_c; idx = i - 1048768; }
    const float4* sp = (const float4*)s;
    float4 a = sp[2 * idx], b = sp[2 * idx + 1];
    union { uint4 v; short sh[8]; } o;
    o.sh[0] = f2bs(a.x); o.sh[1] = f2bs(a.y); o.sh[2] = f2bs(a.z); o.sh[3] = f2bs(a.w);
    o.sh[4] = f2bs(b.x); o.sh[5] = f2bs(b.y); o.sh[6] = f2bs(b.z); o.sh[7] = f2bs(b.w);
    ((uint4*)d)[idx] = o.v;
  } else if (bid < 4865) {
    int l = bid - 4097;  t_cvt_core(Wqa_f, wqaT, 2048, 1536, l % 24, l / 24, Ts);
  } else if (bid < 5153) {
    int l = bid - 4865;  t_cvt_core(Wkva_f, wkvaT, 2048, 576, l % 9, l / 9, Ts);
  } else if (bid < 6305) {
    int l = bid - 5153;  t_cvt_core(Wqb_f, wqbT, 1536, 3072, l % 48, l / 48, Ts);
  } else if (bid < 6817) {
    int l = bid - 6305;  t_cvt_core(Wkvb_f, wkvbT, 512, 4096, l % 64, l / 64, Ts);
  } else {
    int l = bid - 6817;  t_cvt_core(Wo_f, woT, 2048, 2048, l % 32, l / 32, Ts);
  }
}

// ---------------------------------------------------------------------------
// gemm core 256: C = A[M,K] @ BT[N,K]^T. BM=256, BN=128, BK=64, 512 thr =
// 8 waves, 64x64 quadrant each. XOR(row&7)-swizzled LDS, T1 XCD swizzle.
// Split epilogue via C2/ncut (cols >= ncut -> C2[row*640 + col-ncut]).
// ---------------------------------------------------------------------------
template<bool F32OUT>
__device__ __forceinline__ void gemm_core256(
    short* As, short* Bs,
    const bf16* __restrict__ A, const bf16* __restrict__ BT, void* __restrict__ Cv,
    int K, int lda, int ldb, int ldc, bf16* __restrict__ C2, int ncut,
    int nx, int nwg, int lin)
{
  const int tid = threadIdx.x, lane = tid & 63, w = tid >> 6;   // w 0..7
  const int l15 = lane & 15, l4 = lane >> 4;
  const int wr = w >> 1, wc = w & 1;
  const int sl = (lin & 7) * (nwg >> 3) + (lin >> 3);   // nwg % 8 == 0
  const long bm = (long)(sl / nx) * 256, bn = (long)(sl % nx) * 128;
  f32x4 acc[4][4] = {};

  const int srow = tid >> 3;                 // 0..63
  const int scs = (tid & 7) ^ (srow & 7);
  const int rsw = l15 & 7;

  for (int k0 = 0; k0 < K; k0 += 64) {
    __syncthreads();
    #pragma unroll
    for (int j = 0; j < 4; ++j) {
      const unsigned lb = __builtin_amdgcn_readfirstlane((j * 512 + w * 64) * 16);
      gload16(A + (bm + j * 64 + srow) * (long)lda + k0 + scs * 8, (char*)As + lb);
    }
    #pragma unroll
    for (int j = 0; j < 2; ++j) {
      const unsigned lb = __builtin_amdgcn_readfirstlane((j * 512 + w * 64) * 16);
      gload16(BT + (bn + j * 64 + srow) * (long)ldb + k0 + scs * 8, (char*)Bs + lb);
    }
    __syncthreads();
    #pragma unroll
    for (int kk = 0; kk < 2; ++kk) {
      bf16x8 a[4], b[4];
      const int slot = (kk * 4 + l4) ^ rsw;
      #pragma unroll
      for (int mi = 0; mi < 4; ++mi)
        a[mi] = *(const bf16x8*)&As[(wr * 64 + mi * 16 + l15) * 64 + slot * 8];
      #pragma unroll
      for (int ni = 0; ni < 4; ++ni)
        b[ni] = *(const bf16x8*)&Bs[(wc * 64 + ni * 16 + l15) * 64 + slot * 8];
      #pragma unroll
      for (int mi = 0; mi < 4; ++mi)
        #pragma unroll
        for (int ni = 0; ni < 4; ++ni)
          acc[mi][ni] = MFMA16(a[mi], b[ni], acc[mi][ni]);
    }
  }
  #pragma unroll
  for (int mi = 0; mi < 4; ++mi)
    #pragma unroll
    for (int ni = 0; ni < 4; ++ni)
      #pragma unroll
      for (int r = 0; r < 4; ++r) {
        long row = bm + wr * 64 + mi * 16 + l4 * 4 + r;
        long col = bn + wc * 64 + ni * 16 + l15;
        float v = acc[mi][ni][r];
        if (F32OUT) {
          ((float*)Cv)[row * ldc + col] = v;
        } else if (C2 && col >= ncut) {
          C2[row * 640 + (col - ncut)] = __float2bfloat16(v);
        } else {
          ((bf16*)Cv)[row * (long)ldc + col] = __float2bfloat16(v);
        }
      }
}

template<bool F32OUT>
__global__ __launch_bounds__(512) void gemm_v5(
    const bf16* __restrict__ A, const bf16* __restrict__ BT, void* __restrict__ Cv,
    int K, int lda, int ldb, int ldc, bf16* __restrict__ C2, int ncut)
{
  __shared__ __align__(16) short As[256 * 64];
  __shared__ __align__(16) short Bs[128 * 64];
  const int nx = gridDim.x, nwg = nx * gridDim.y;
  const int lin = blockIdx.y * nx + blockIdx.x;
  gemm_core256<F32OUT>(As, Bs, A, BT, Cv, K, lda, ldb, ldc, C2, ncut, nx, nwg, lin);
}

// ---------------------------------------------------------------------------
// gemm_dual (512 thr): blocks 0..383 -> q = ckq@WqbT; 384..895 -> kv GEMM
// with fused K/V assembly (two 128-row halves staged through LDS, coalesced
// uint4 global writes; TS_S=139 avoids the cs-column bank alias).
// ---------------------------------------------------------------------------
#define TS_S 139
__global__ __launch_bounds__(512) void gemm_dual(
    const bf16* __restrict__ ckq, const bf16* __restrict__ wqbT, bf16* __restrict__ q,
    const bf16* __restrict__ kvns, const bf16* __restrict__ wkvbT,
    bf16* __restrict__ Kf, bf16* __restrict__ Vt)
{
  __shared__ __align__(16) short LDSU[256 * 64 + 128 * 64];  // 48 KB
  short* As = LDSU;
  short* Bs = LDSU + 256 * 64;
  const int bid = blockIdx.x;
  if (bid < 384) {
    gemm_core256<false>(As, Bs, ckq, wqbT, q, 1536, 1536, 1536, 3072, nullptr, 0,
                        24, 384, bid);
    return;
  }
  // ---- kv segment: 512 blocks, BM=256, BN=128, K=512 ----
  const int lin = bid - 384;
  const int tid = threadIdx.x, lane = tid & 63, w = tid >> 6;
  const int l15 = lane & 15, l4 = lane >> 4;
  const int wr = w >> 1, wc = w & 1;
  const int sl = (lin & 7) * 64 + (lin >> 3);     // nwg=512
  const long bm = (long)(sl / 32) * 256, bn = (long)(sl % 32) * 128;
  f32x4 acc[4][4] = {};
  const int srow = tid >> 3;
  const int scs = (tid & 7) ^ (srow & 7);
  const int rsw = l15 & 7;

  for (int k0 = 0; k0 < 512; k0 += 64) {
    __syncthreads();
    #pragma unroll
    for (int j = 0; j < 4; ++j) {
      const unsigned lb = __builtin_amdgcn_readfirstlane((j * 512 + w * 64) * 16);
      gload16(kvns + (bm + j * 64 + srow) * 640L + k0 + scs * 8, (char*)As + lb);
    }
    #pragma unroll
    for (int j = 0; j < 2; ++j) {
      const unsigned lb = __builtin_amdgcn_readfirstlane((j * 512 + w * 64) * 16);
      gload16(wkvbT + (bn + j * 64 + srow) * 512L + k0 + scs * 8, (char*)Bs + lb);
    }
    __syncthreads();
    #pragma unroll
    for (int kk = 0; kk < 2; ++kk) {
      bf16x8 a[4], b[4];
      const int slot = (kk * 4 + l4) ^ rsw;
      #pragma unroll
      for (int mi = 0; mi < 4; ++mi)
        a[mi] = *(const bf16x8*)&As[(wr * 64 + mi * 16 + l15) * 64 + slot * 8];
      #pragma unroll
      for (int ni = 0; ni < 4; ++ni)
        b[ni] = *(const bf16x8*)&Bs[(wc * 64 + ni * 16 + l15) * 64 + slot * 8];
      #pragma unroll
      for (int mi = 0; mi < 4; ++mi)
        #pragma unroll
        for (int ni = 0; ni < 4; ++ni)
          acc[mi][ni] = MFMA16(a[mi], b[ni], acc[mi][ni]);
    }
  }

  const int h = (int)(bn >> 8);
  const int lc = (int)(bn & 255);                // 0 = k_nope, 128 = v
  const int bh = (int)(bm >> 11) * 16 + h;
  const int tsb = (int)(bm & 2047);

  #pragma unroll
  for (int hf = 0; hf < 2; ++hf) {
    __syncthreads();
    if ((wr >> 1) == hf) {   // waves owning rows [hf*128, hf*128+128)
      #pragma unroll
      for (int mi = 0; mi < 4; ++mi)
        #pragma unroll
        for (int ni = 0; ni < 4; ++ni)
          #pragma unroll
          for (int r = 0; r < 4; ++r)
            LDSU[((wr & 1) * 64 + mi * 16 + l4 * 4 + r) * TS_S +
                 wc * 64 + ni * 16 + l15] = f2bs(acc[mi][ni][r]);
    }
    __syncthreads();
    if (lc == 0) {
      #pragma unroll
      for (int j = 0; j < 4; ++j) {
        int u = j * 512 + tid;
        int tl = u >> 4, cs = u & 15;
        union { uint4 v; short sh[8]; } o;
        #pragma unroll
        for (int i = 0; i < 8; ++i) o.sh[i] = LDSU[tl * TS_S + cs * 8 + i];
        int t = tsb + hf * 128 + tl;
        *(uint4*)(Kf + ((size_t)bh * 2048 + t) * 192 + ((cs ^ (t & 7)) << 3)) = o.v;
      }
    } else {
      #pragma unroll
      for (int j = 0; j < 4; ++j) {
        int u = j * 512 + tid;
        int d = u >> 4, slo = u & 15;
        int k0l = (slo >> 3) << 6;     // 0 or 64
        int cs = slo & 7;
        int tb = k0l + cs * 8;
        union { uint4 v; short sh[8]; } o;
        #pragma unroll
        for (int i = 0; i < 8; ++i) o.sh[i] = LDSU[(tb + i) * TS_S + d];
        *(uint4*)(Vt + ((size_t)(bh * 128 + d)) * 2048 + tsb + hf * 128 + k0l +
                  ((cs ^ (d & 7)) << 3)) = o.v;
      }
    }
  }
}

// ---------------------------------------------------------------------------
// rms_pe_dual: blocks 0..4095 -> rms ckq; 4096..8191 -> rms kvns + fused
// k_pe rope -> Kf pe slots (stored 16..23).
// ---------------------------------------------------------------------------
template<int C>
__device__ __forceinline__ void rms_core(bf16* __restrict__ xr,
                                         const bf16* __restrict__ w, float* red)
{
  constexpr int PER = C / 256;
  const int tid = threadIdx.x;
  float v[PER];
  float ss = 0.f;
  #pragma unroll
  for (int k = 0; k < PER; ++k) {
    float f = __bfloat162float(xr[tid + k * 256]);
    v[k] = f; ss += f * f;
  }
  #pragma unroll
  for (int off = 1; off < 64; off <<= 1) ss += __shfl_xor(ss, off);
  if ((tid & 63) == 0) red[tid >> 6] = ss;
  __syncthreads();
  float tot = red[0] + red[1] + red[2] + red[3];
  float scale = rsqrtf(tot / (float)C + 1e-6f);
  #pragma unroll
  for (int k = 0; k < PER; ++k)
    xr[tid + k * 256] =
        __float2bfloat16(v[k] * scale * __bfloat162float(w[tid + k * 256]));
}

__global__ __launch_bounds__(256) void rms_pe_dual(bf16* __restrict__ ckq,
                                                   const bf16* __restrict__ qw,
                                                   bf16* __restrict__ kvns,
                                                   const bf16* __restrict__ kvw,
                                                   bf16* __restrict__ Kf)
{
  __shared__ float red[4];
  __shared__ short pe[64];
  const int bid = blockIdx.x, tid = threadIdx.x;
  if (bid < 4096) {
    rms_core<1536>(ckq + (long)bid * 1536, qw, red);
    return;
  }
  const int t = bid - 4096;
  rms_core<512>(kvns + (long)t * 640, kvw, red);
  if (tid < 32) {
    int i = tid;
    float p = (float)(t & 2047);
    float freq = powf(10000.0f, -(float)i / 32.0f);
    float sn, cs;
    sincosf(p * freq, &sn, &cs);
    float y1 = __bfloat162float(kvns[(long)t * 640 + 512 + 2 * i]);
    float y2 = __bfloat162float(kvns[(long)t * 640 + 512 + 2 * i + 1]);
    pe[2 * i]     = f2bs(y1 * cs - y2 * sn);
    pe[2 * i + 1] = f2bs(y2 * cs + y1 * sn);
  }
  __syncthreads();
  if (tid < 128) {
    const int hh = tid >> 3, j = tid & 7;
    const int swz = t & 7;
    const int b = t >> 11, ts = t & 2047;
    uint4 val = *(const uint4*)&pe[(j ^ swz) * 8];
    *(uint4*)(Kf + ((size_t)(b * 16 + hh) * 2048 + ts) * 192 + (16 + j) * 8) = val;
  }
}

// ---------------------------------------------------------------------------
// attn_v6 (r18-measured best): swapped-QK softmax + pairing + fused Q-RoPE,
// exp2, single-buffer Ks (K(c+1) issued after mid-barrier).
// ---------------------------------------------------------------------------
__global__ __launch_bounds__(256) void attn_v6(const bf16* __restrict__ q,
                                               const bf16* __restrict__ Kf,
                                               const bf16* __restrict__ Vt,
                                               bf16* __restrict__ attn)
{
  __shared__ __align__(16) short Ks[64 * 192];
  __shared__ __align__(16) short Vs[128 * 64];
  __shared__ __align__(16) short Ps[4][16 * 64];
  const float SC2 = 0.10411442245076847f;  // 192^-0.5 * log2(e)
  const int tid = threadIdx.x, lane = tid & 63, w = tid >> 6;
  const int l15 = lane & 15, l4 = lane >> 4;
  const int lin = blockIdx.x;
  const int x = lin & 7, j = lin >> 3;
  const int bh = x * 4 + (j >> 4), p = j & 15;
  const int b = bh >> 4, h = bh & 15;
  const unsigned lbase = __builtin_amdgcn_readfirstlane(w * 64 * 16);

  #pragma unroll
  for (int half = 0; half < 2; ++half) {
    const int qt = half ? (31 - p) : p;
    const long qrow0 = (long)b * 2048 + qt * 64;
    const int rowt = qt * 64 + w * 16 + l15;

    bf16x8 qf[6];
    {
      const short* qrow = (const short*)q + (qrow0 + w * 16 + l15) * 3072 + h * 192;
      #pragma unroll
      for (int kc = 0; kc < 6; ++kc)
        qf[kc] = *(const bf16x8*)(qrow + kc * 32 + l4 * 8);
    }
    {  // fused GPT-J RoPE on pe fragments (cols 128..191 = kc 4,5)
      float pos = (float)rowt;
      #pragma unroll
      for (int kc = 4; kc < 6; ++kc)
        #pragma unroll
        for (int pr = 0; pr < 4; ++pr) {
          int i = (kc - 4) * 16 + l4 * 4 + pr;
          float freq = __expf((float)i * -0.28782313662425572f);  // 10000^(-i/32)
          float sn, cs;
          sincosf(pos * freq, &sn, &cs);
          float x1 = bs2f(qf[kc][2 * pr]), x2 = bs2f(qf[kc][2 * pr + 1]);
          qf[kc][2 * pr]     = f2bs(x1 * cs - x2 * sn);
          qf[kc][2 * pr + 1] = f2bs(x2 * cs + x1 * sn);
        }
    }
    f32x4 o[8] = {};
    float mreg = -1e30f, ls = 0.f;
    const int nch = qt + 1;

    {  // prologue: stage K chunk 0
      const char* ksrc = (const char*)(Kf + (long)bh * 2048 * 192);
      #pragma unroll
      for (int jj = 0; jj < 6; ++jj)
        gload16(ksrc + (jj * 256 + tid) * 16, (char*)Ks + jj * 4096 + lbase);
    }
    __syncthreads();

    for (int c = 0; c < nch; ++c) {
      const int k0 = c * 64;
      {  // issue V(c) — drains at mid-barrier, hidden under QK+softmax
        #pragma unroll
        for (int jj = 0; jj < 4; ++jj) {
          int seg = jj * 256 + tid;
          const bf16* vsrc = Vt + ((long)bh * 128 + (seg >> 3)) * 2048 + k0 + (seg & 7) * 8;
          gload16(vsrc, (char*)Vs + jj * 4096 + lbase);
        }
      }
      __builtin_amdgcn_s_setprio(1);
      f32x4 s[4] = {};
      #pragma unroll
      for (int kc = 0; kc < 6; ++kc)
        #pragma unroll
        for (int kg = 0; kg < 4; ++kg) {
          int row = kg * 16 + l15;
          int slot = (kc * 4 + l4) ^ (l15 & 7);
          bf16x8 kb = *(const bf16x8*)&Ks[row * 192 + slot * 8];
          s[kg] = MFMA16(kb, qf[kc], s[kg]);   // SWAPPED: D[key][qrow]
        }
      __builtin_amdgcn_s_setprio(0);

      const bool diag = (c == qt);
      float pk[16];
      #pragma unroll
      for (int kg = 0; kg < 4; ++kg)
        #pragma unroll
        for (int r = 0; r < 4; ++r) {
          float v = s[kg][r];
          if (diag && (k0 + kg * 16 + l4 * 4 + r > rowt)) v = -1e30f;
          pk[kg * 4 + r] = v;
        }
      float cm = pk[0];
      #pragma unroll
      for (int i = 1; i < 16; ++i) cm = fmaxf(cm, pk[i]);
      cm = fmaxf(cm, __shfl_xor(cm, 16));
      cm = fmaxf(cm, __shfl_xor(cm, 32));
      cm *= SC2;  // scale once (monotone)
      if (__ballot(cm > mreg + 12.0f)) {  // defer-max rescale (wave-uniform)
        float mn = fmaxf(mreg, cm);
        float al = exp2f(mreg - mn);
        ls *= al;
        float af[4];
        #pragma unroll
        for (int r = 0; r < 4; ++r) af[r] = __shfl(al, l4 * 4 + r);
        #pragma unroll
        for (int f = 0; f < 8; ++f)
          #pragma unroll
          for (int r = 0; r < 4; ++r) o[f][r] *= af[r];
        mreg = mn;
      }
      float ps = 0.f;
      #pragma unroll
      for (int i = 0; i < 16; ++i) {
        pk[i] = exp2f(fmaf(pk[i], SC2, -mreg));
        ps += pk[i];
      }
      ps += __shfl_xor(ps, 16);
      ps += __shfl_xor(ps, 32);
      ls += ps;
      #pragma unroll
      for (int kg = 0; kg < 4; ++kg)
        #pragma unroll
        for (int pr = 0; pr < 2; ++pr) {
          int key2 = kg * 16 + l4 * 4 + pr * 2;
          int sl = (key2 >> 3) ^ (l15 & 7);
          unsigned lo = (unsigned short)f2bs(pk[kg * 4 + pr * 2]);
          unsigned hi = (unsigned short)f2bs(pk[kg * 4 + pr * 2 + 1]);
          *(unsigned*)&Ps[w][l15 * 64 + sl * 8 + (key2 & 7)] = lo | (hi << 16);
        }
      __syncthreads();  // mid-barrier: V(c) landed; Ks reads + Ps writes done

      if (c + 1 < nch) {  // issue K(c+1) — drains at end-barrier, under PV
        const char* ksrc = (const char*)(Kf + ((long)bh * 2048 + k0 + 64) * 192);
        #pragma unroll
        for (int jj = 0; jj < 6; ++jj)
          gload16(ksrc + (jj * 256 + tid) * 16, (char*)Ks + jj * 4096 + lbase);
      }

      __builtin_amdgcn_s_setprio(1);
      #pragma unroll
      for (int ks = 0; ks < 2; ++ks) {
        int psl = (ks * 4 + l4) ^ (l15 & 7);
        bf16x8 pa = *(const bf16x8*)&Ps[w][l15 * 64 + psl * 8];
        #pragma unroll
        for (int f = 0; f < 8; ++f) {
          int vrow = f * 16 + l15;
          int vsl = (ks * 4 + l4) ^ (l15 & 7);
          bf16x8 bv = *(const bf16x8*)&Vs[vrow * 64 + vsl * 8];
          o[f] = MFMA16(pa, bv, o[f]);
        }
      }
      __builtin_amdgcn_s_setprio(0);
      __syncthreads();  // end-barrier: K(c+1) landed; Vs reads done
    }

    #pragma unroll
    for (int r = 0; r < 4; ++r) {
      float lsr = __shfl(ls, l4 * 4 + r);
      float inv = 1.0f / lsr;
      long t = qrow0 + w * 16 + l4 * 4 + r;
      bf16* dst = attn + t * 2048 + h * 128;
      #pragma unroll
      for (int f = 0; f < 8; ++f)
        dst[f * 16 + l15] = __float2bfloat16(o[f][r] * inv);
    }
  }
}

// ---------------------------------------------------------------------------
extern "C" void kernel_launch(void* const* d_in, const int* in_sizes, int n_in,
                              void* d_out, int out_size, void* d_ws, size_t ws_size,
                              hipStream_t stream) {
  const float* hs_f   = (const float*)d_in[1];
  const float* Wqa_f  = (const float*)d_in[2];
  const float* qln_f  = (const float*)d_in[3];
  const float* Wqb_f  = (const float*)d_in[4];
  const float* Wkva_f = (const float*)d_in[5];
  const float* kvln_f = (const float*)d_in[6];
  const float* Wkvb_f = (const float*)d_in[7];
  const float* Wo_f   = (const float*)d_in[8];

  bf16* base = (bf16*)d_ws;
  bf16* hs_c  = base;                       // 8,388,608 (dead after gemmA) | q overlay
  bf16* wqaT  = base + 8388608;             // 3,145,728
  bf16* wkvaT = base + 11534336;            // 1,179,648 (ends 12,713,984)
  bf16* q     = base;                       // 12,582,912 overlay (gemm_dual+)
  bf16* ckq   = base + 12713984;            // 6,291,456 (dead after gemm_dual)
  bf16* qln_c = base + 19005440;            // 1536
  bf16* kvln_c= base + 19006976;            // 512   (ends 19,007,488)
  bf16* attnb = base + 12713984;            // 8,388,608 overlay over ckq+ln (attn+)
  bf16* wqbT  = base + 21102592;            // 4,718,592
  bf16* wkvbT = base + 25821184;            // 2,097,152
  bf16* woT   = base + 27918336;            // 4,194,304 (alive till gemmW)
  bf16* kvns  = base + 32112640;            // 2,621,440
  bf16* Kf    = base + 34734080;            // 12,582,912
  bf16* Vt    = base + 47316992;            // 8,388,608 (ends 55,705,600 = 111.4 MB)

  // 1) mega-prep: all conversions + all weight transposes
  prep_all<<<7841, 256, 0, stream>>>(hs_f, hs_c, qln_f, qln_c, kvln_f, kvln_c,
                                     Wqa_f, wqaT, Wkva_f, wkvaT,
                                     Wqb_f, wqbT, Wkvb_f, wkvbT, Wo_f, woT);
  // 2) fused: [ckq | kvns] = hs @ [Wqa | Wkva]  (N=2176, split at 1536)
  gemm_v5<false><<<dim3(17, 16), 512, 0, stream>>>(hs_c, wqaT, ckq, 2048,
                                                   2048, 2048, 1536, kvns, 1536);
  // 3) rmsnorms + fused k_pe rope -> Kf
  rms_pe_dual<<<8192, 256, 0, stream>>>(ckq, qln_c, kvns, kvln_c, Kf);
  // 4) merged: q = ckq@WqbT (over dead hs/wqaT/wkvaT) | {Kf, Vt} = kvns@WkvbT
  gemm_dual<<<896, 512, 0, stream>>>(ckq, wqbT, q, kvns, wkvbT, Kf, Vt);
  // 5) attention (r18-proven v6 schedule)
  attn_v6<<<512, 256, 0, stream>>>(q, Kf, Vt, attnb);
  // 6) out = attn @ Wo (f32 output)
  gemm_v5<true><<<dim3(16, 16), 512, 0, stream>>>(attnb, woT, d_out, 2048,
                                                  2048, 2048, 2048, nullptr, 0);
}

// Round 21
// 279.515 us; speedup vs baseline: 1.0600x; 1.0600x over previous
//
#include <hip/hip_runtime.h>
#include <hip/hip_bf16.h>

typedef __hip_bfloat16 bf16;
typedef short bf16x8 __attribute__((ext_vector_type(8)));
typedef float f32x4 __attribute__((ext_vector_type(4)));

#define MFMA16(a, b, c) __builtin_amdgcn_mfma_f32_16x16x32_bf16((a), (b), (c), 0, 0, 0)

__device__ __forceinline__ short f2bs(float f) {
  bf16 h = __float2bfloat16(f);
  return __builtin_bit_cast(short, h);
}
__device__ __forceinline__ float bs2f(short s) {
  return __bfloat162float(__builtin_bit_cast(bf16, s));
}

// async global->LDS, 16B per lane; LDS dest = wave-uniform base + lane*16
__device__ __forceinline__ void gload16(const void* g, const void* l) {
  __builtin_amdgcn_global_load_lds(
      (const __attribute__((address_space(1))) unsigned int*)g,
      (__attribute__((address_space(3))) unsigned int*)l, 16, 0, 0);
}

// ---------------------------------------------------------------------------
// f32->bf16 transpose core: dst[N][K](bf16) = src[K][N](f32)^T, 64x64 tile.
// ---------------------------------------------------------------------------
__device__ __forceinline__ void t_cvt_core(const float* __restrict__ src,
                                           bf16* __restrict__ dst, int K, int N,
                                           int bx, int by, short Ts[64][72]) {
  const long n0 = (long)bx * 64, k0 = (long)by * 64;
  const int r = threadIdx.x >> 2, c4 = threadIdx.x & 3;
  const float* s = src + (k0 + r) * (long)N + n0 + c4 * 16;
  #pragma unroll
  for (int j = 0; j < 4; ++j) {
    float4 v = *(const float4*)(s + j * 4);
    Ts[r][c4 * 16 + j * 4 + 0] = f2bs(v.x);
    Ts[r][c4 * 16 + j * 4 + 1] = f2bs(v.y);
    Ts[r][c4 * 16 + j * 4 + 2] = f2bs(v.z);
    Ts[r][c4 * 16 + j * 4 + 3] = f2bs(v.w);
  }
  __syncthreads();
  union { uint4 v; short sh[8]; } o0, o1;
  #pragma unroll
  for (int j = 0; j < 8; ++j) o0.sh[j] = Ts[c4 * 16 + j][r];
  #pragma unroll
  for (int j = 0; j < 8; ++j) o1.sh[j] = Ts[c4 * 16 + 8 + j][r];
  *(uint4*)(dst + (n0 + r) * (long)K + k0 + c4 * 16)     = o0.v;
  *(uint4*)(dst + (n0 + r) * (long)K + k0 + c4 * 16 + 8) = o1.v;
}

// ---------------------------------------------------------------------------
// mega-prep: flat cvt (hs, q_ln, kv_ln) + ALL five weight transposes. 7841 blk.
// ---------------------------------------------------------------------------
__global__ __launch_bounds__(256) void prep_all(
    const float* __restrict__ hs_f, bf16* __restrict__ hs_c,
    const float* __restrict__ qln_f, bf16* __restrict__ qln_c,
    const float* __restrict__ kvln_f, bf16* __restrict__ kvln_c,
    const float* __restrict__ Wqa_f, bf16* __restrict__ wqaT,
    const float* __restrict__ Wkva_f, bf16* __restrict__ wkvaT,
    const float* __restrict__ Wqb_f, bf16* __restrict__ wqbT,
    const float* __restrict__ Wkvb_f, bf16* __restrict__ wkvbT,
    const float* __restrict__ Wo_f, bf16* __restrict__ woT)
{
  __shared__ __align__(16) short Ts[64][72];
  const int bid = blockIdx.x;
  if (bid < 4097) {
    int i = bid * 256 + threadIdx.x;
    const float* s; bf16* d; int idx;
    if (i < 1048576)            { s = hs_f;   d = hs_c;   idx = i; }
    else if (i < 1048576 + 192) { s = qln_f;  d = qln_c;  idx = i - 1048576; }
    else                        { s = kvln_f; d = kvln_c; idx = i - 1048768; }
    const float4* sp = (const float4*)s;
    float4 a = sp[2 * idx], b = sp[2 * idx + 1];
    union { uint4 v; short sh[8]; } o;
    o.sh[0] = f2bs(a.x); o.sh[1] = f2bs(a.y); o.sh[2] = f2bs(a.z); o.sh[3] = f2bs(a.w);
    o.sh[4] = f2bs(b.x); o.sh[5] = f2bs(b.y); o.sh[6] = f2bs(b.z); o.sh[7] = f2bs(b.w);
    ((uint4*)d)[idx] = o.v;
  } else if (bid < 4865) {
    int l = bid - 4097;  t_cvt_core(Wqa_f, wqaT, 2048, 1536, l % 24, l / 24, Ts);
  } else if (bid < 5153) {
    int l = bid - 4865;  t_cvt_core(Wkva_f, wkvaT, 2048, 576, l % 9, l / 9, Ts);
  } else if (bid < 6305) {
    int l = bid - 5153;  t_cvt_core(Wqb_f, wqbT, 1536, 3072, l % 48, l / 48, Ts);
  } else if (bid < 6817) {
    int l = bid - 6305;  t_cvt_core(Wkvb_f, wkvbT, 512, 4096, l % 64, l / 64, Ts);
  } else {
    int l = bid - 6817;  t_cvt_core(Wo_f, woT, 2048, 2048, l % 32, l / 32, Ts);
  }
}

// ---------------------------------------------------------------------------
// gemm core (r18-proven): C = A[M,K] @ BT[N,K]^T. BM=BN=128, BK=64, 4 waves.
// XOR(row&7)-swizzled LDS, T1 XCD swizzle. Split epilogue via C2/ncut.
// ---------------------------------------------------------------------------
template<bool F32OUT>
__device__ __forceinline__ void gemm_core(
    short* As, short* Bs,
    const bf16* __restrict__ A, const bf16* __restrict__ BT, void* __restrict__ Cv,
    int N, int K, int lda, int ldb, int ldc, bf16* __restrict__ C2, int ncut,
    int nx, int nwg, int lin)
{
  const int tid = threadIdx.x, lane = tid & 63, w = tid >> 6;
  const int l15 = lane & 15, l4 = lane >> 4;
  const int wr = w >> 1, wc = w & 1;
  const int sl = (lin & 7) * (nwg >> 3) + (lin >> 3);   // nwg % 8 == 0
  const long bm = (long)(sl / nx) * 128, bn = (long)(sl % nx) * 128;
  f32x4 acc[4][4] = {};

  const int srow = tid >> 3;
  const int scs = (tid & 7) ^ (srow & 7);
  const int rsw = l15 & 7;

  for (int k0 = 0; k0 < K; k0 += 64) {
    __syncthreads();
    #pragma unroll
    for (int j = 0; j < 4; ++j) {
      const unsigned lb = __builtin_amdgcn_readfirstlane((j * 256 + w * 64) * 16);
      gload16(A + (bm + j * 32 + srow) * (long)lda + k0 + scs * 8, (char*)As + lb);
      gload16(BT + (bn + j * 32 + srow) * (long)ldb + k0 + scs * 8, (char*)Bs + lb);
    }
    __syncthreads();
    #pragma unroll
    for (int kk = 0; kk < 2; ++kk) {
      bf16x8 a[4], b[4];
      const int slot = (kk * 4 + l4) ^ rsw;
      #pragma unroll
      for (int mi = 0; mi < 4; ++mi)
        a[mi] = *(const bf16x8*)&As[(wr * 64 + mi * 16 + l15) * 64 + slot * 8];
      #pragma unroll
      for (int ni = 0; ni < 4; ++ni)
        b[ni] = *(const bf16x8*)&Bs[(wc * 64 + ni * 16 + l15) * 64 + slot * 8];
      #pragma unroll
      for (int mi = 0; mi < 4; ++mi)
        #pragma unroll
        for (int ni = 0; ni < 4; ++ni)
          acc[mi][ni] = MFMA16(a[mi], b[ni], acc[mi][ni]);
    }
  }
  #pragma unroll
  for (int mi = 0; mi < 4; ++mi)
    #pragma unroll
    for (int ni = 0; ni < 4; ++ni)
      #pragma unroll
      for (int r = 0; r < 4; ++r) {
        long row = bm + wr * 64 + mi * 16 + l4 * 4 + r;
        long col = bn + wc * 64 + ni * 16 + l15;
        float v = acc[mi][ni][r];
        if (F32OUT) {
          ((float*)Cv)[row * ldc + col] = v;
        } else if (C2 && col >= ncut) {
          C2[row * 640 + (col - ncut)] = __float2bfloat16(v);
        } else {
          ((bf16*)Cv)[row * (long)ldc + col] = __float2bfloat16(v);
        }
      }
}

template<bool F32OUT>
__global__ __launch_bounds__(256) void gemm_v4(
    const bf16* __restrict__ A, const bf16* __restrict__ BT, void* __restrict__ Cv,
    int N, int K, int lda, int ldb, int ldc, bf16* __restrict__ C2, int ncut)
{
  __shared__ __align__(16) short As[128 * 64];
  __shared__ __align__(16) short Bs[128 * 64];
  const int nx = gridDim.x, nwg = nx * gridDim.y;
  const int lin = blockIdx.y * nx + blockIdx.x;
  gemm_core<F32OUT>(As, Bs, A, BT, Cv, N, K, lda, ldb, ldc, C2, ncut, nx, nwg, lin);
}

// ---------------------------------------------------------------------------
// gemm_dual (r18-proven, 256 thr): blocks 0..767 -> q = ckq@WqbT;
// 768..1791 -> kv GEMM with fused K/V assembly (LDS-staged coalesced writes).
// ---------------------------------------------------------------------------
#define TS_S 139
__global__ __launch_bounds__(256) void gemm_dual(
    const bf16* __restrict__ ckq, const bf16* __restrict__ wqbT, bf16* __restrict__ q,
    const bf16* __restrict__ kvns, const bf16* __restrict__ wkvbT,
    bf16* __restrict__ Kf, bf16* __restrict__ Vt)
{
  __shared__ __align__(16) short LDSU[128 * TS_S];   // 35.6 KB
  short* As = LDSU;
  short* Bs = LDSU + 8192;
  const int bid = blockIdx.x;
  if (bid < 768) {
    gemm_core<false>(As, Bs, ckq, wqbT, q, 3072, 1536, 1536, 1536, 3072, nullptr, 0,
                     24, 768, bid);
    return;
  }
  const int lin = bid - 768;
  const int tid = threadIdx.x, lane = tid & 63, w = tid >> 6;
  const int l15 = lane & 15, l4 = lane >> 4;
  const int wr = w >> 1, wc = w & 1;
  const int sl = (lin & 7) * 128 + (lin >> 3);   // nwg=1024
  const long bm = (long)(sl / 32) * 128, bn = (long)(sl % 32) * 128;
  f32x4 acc[4][4] = {};
  const int srow = tid >> 3;
  const int scs = (tid & 7) ^ (srow & 7);
  const int rsw = l15 & 7;

  for (int k0 = 0; k0 < 512; k0 += 64) {
    __syncthreads();
    #pragma unroll
    for (int j = 0; j < 4; ++j) {
      const unsigned lb = __builtin_amdgcn_readfirstlane((j * 256 + w * 64) * 16);
      gload16(kvns + (bm + j * 32 + srow) * 640L + k0 + scs * 8, (char*)As + lb);
      gload16(wkvbT + (bn + j * 32 + srow) * 512L + k0 + scs * 8, (char*)Bs + lb);
    }
    __syncthreads();
    #pragma unroll
    for (int kk = 0; kk < 2; ++kk) {
      bf16x8 a[4], b[4];
      const int slot = (kk * 4 + l4) ^ rsw;
      #pragma unroll
      for (int mi = 0; mi < 4; ++mi)
        a[mi] = *(const bf16x8*)&As[(wr * 64 + mi * 16 + l15) * 64 + slot * 8];
      #pragma unroll
      for (int ni = 0; ni < 4; ++ni)
        b[ni] = *(const bf16x8*)&Bs[(wc * 64 + ni * 16 + l15) * 64 + slot * 8];
      #pragma unroll
      for (int mi = 0; mi < 4; ++mi)
        #pragma unroll
        for (int ni = 0; ni < 4; ++ni)
          acc[mi][ni] = MFMA16(a[mi], b[ni], acc[mi][ni]);
    }
  }

  const int h = (int)(bn >> 8);
  const int lc = (int)(bn & 255);                // 0 = k_nope, 128 = v
  const int bh = (int)(bm >> 11) * 16 + h;
  const int tsb = (int)(bm & 2047);

  __syncthreads();
  #pragma unroll
  for (int mi = 0; mi < 4; ++mi)
    #pragma unroll
    for (int ni = 0; ni < 4; ++ni)
      #pragma unroll
      for (int r = 0; r < 4; ++r)
        LDSU[(wr * 64 + mi * 16 + l4 * 4 + r) * TS_S + wc * 64 + ni * 16 + l15] =
            f2bs(acc[mi][ni][r]);
  __syncthreads();

  if (lc == 0) {
    #pragma unroll
    for (int j = 0; j < 8; ++j) {
      int u = j * 256 + tid;
      int tl = u >> 4, cs = u & 15;
      union { uint4 v; short sh[8]; } o;
      #pragma unroll
      for (int i = 0; i < 8; ++i) o.sh[i] = LDSU[tl * TS_S + cs * 8 + i];
      *(uint4*)(Kf + ((size_t)bh * 2048 + tsb + tl) * 192 +
                ((cs ^ (tl & 7)) << 3)) = o.v;
    }
  } else {
    #pragma unroll
    for (int j = 0; j < 8; ++j) {
      int u = j * 256 + tid;
      int d = u >> 4, slo = u & 15;
      int k0l = (slo >> 3) << 6;     // 0 or 64
      int cs = slo & 7;
      int tb = k0l + cs * 8;
      union { uint4 v; short sh[8]; } o;
      #pragma unroll
      for (int i = 0; i < 8; ++i) o.sh[i] = LDSU[(tb + i) * TS_S + d];
      *(uint4*)(Vt + ((size_t)(bh * 128 + d)) * 2048 + tsb + k0l +
                ((cs ^ (d & 7)) << 3)) = o.v;
    }
  }
}

// ---------------------------------------------------------------------------
// rms_pe_dual: blocks 0..4095 -> rms ckq; 4096..8191 -> rms kvns + fused
// k_pe rope -> Kf pe slots (stored 16..23).
// ---------------------------------------------------------------------------
template<int C>
__device__ __forceinline__ void rms_core(bf16* __restrict__ xr,
                                         const bf16* __restrict__ w, float* red)
{
  constexpr int PER = C / 256;
  const int tid = threadIdx.x;
  float v[PER];
  float ss = 0.f;
  #pragma unroll
  for (int k = 0; k < PER; ++k) {
    float f = __bfloat162float(xr[tid + k * 256]);
    v[k] = f; ss += f * f;
  }
  #pragma unroll
  for (int off = 1; off < 64; off <<= 1) ss += __shfl_xor(ss, off);
  if ((tid & 63) == 0) red[tid >> 6] = ss;
  __syncthreads();
  float tot = red[0] + red[1] + red[2] + red[3];
  float scale = rsqrtf(tot / (float)C + 1e-6f);
  #pragma unroll
  for (int k = 0; k < PER; ++k)
    xr[tid + k * 256] =
        __float2bfloat16(v[k] * scale * __bfloat162float(w[tid + k * 256]));
}

__global__ __launch_bounds__(256) void rms_pe_dual(bf16* __restrict__ ckq,
                                                   const bf16* __restrict__ qw,
                                                   bf16* __restrict__ kvns,
                                                   const bf16* __restrict__ kvw,
                                                   bf16* __restrict__ Kf)
{
  __shared__ float red[4];
  __shared__ short pe[64];
  const int bid = blockIdx.x, tid = threadIdx.x;
  if (bid < 4096) {
    rms_core<1536>(ckq + (long)bid * 1536, qw, red);
    return;
  }
  const int t = bid - 4096;
  rms_core<512>(kvns + (long)t * 640, kvw, red);
  if (tid < 32) {
    int i = tid;
    float p = (float)(t & 2047);
    float freq = powf(10000.0f, -(float)i / 32.0f);
    float sn, cs;
    sincosf(p * freq, &sn, &cs);
    float y1 = __bfloat162float(kvns[(long)t * 640 + 512 + 2 * i]);
    float y2 = __bfloat162float(kvns[(long)t * 640 + 512 + 2 * i + 1]);
    pe[2 * i]     = f2bs(y1 * cs - y2 * sn);
    pe[2 * i + 1] = f2bs(y2 * cs + y1 * sn);
  }
  __syncthreads();
  if (tid < 128) {
    const int hh = tid >> 3, j = tid & 7;
    const int swz = t & 7;
    const int b = t >> 11, ts = t & 2047;
    uint4 val = *(const uint4*)&pe[(j ^ swz) * 8];
    *(uint4*)(Kf + ((size_t)(b * 16 + hh) * 2048 + ts) * 192 + (16 + j) * 8) = val;
  }
}

// ---------------------------------------------------------------------------
// attn_v6 (r18-measured best): swapped-QK softmax + pairing + fused Q-RoPE,
// exp2, single-buffer Ks (K(c+1) issued after mid-barrier).
// ---------------------------------------------------------------------------
__global__ __launch_bounds__(256) void attn_v6(const bf16* __restrict__ q,
                                               const bf16* __restrict__ Kf,
                                               const bf16* __restrict__ Vt,
                                               bf16* __restrict__ attn)
{
  __shared__ __align__(16) short Ks[64 * 192];
  __shared__ __align__(16) short Vs[128 * 64];
  __shared__ __align__(16) short Ps[4][16 * 64];
  const float SC2 = 0.10411442245076847f;  // 192^-0.5 * log2(e)
  const int tid = threadIdx.x, lane = tid & 63, w = tid >> 6;
  const int l15 = lane & 15, l4 = lane >> 4;
  const int lin = blockIdx.x;
  const int x = lin & 7, j = lin >> 3;
  const int bh = x * 4 + (j >> 4), p = j & 15;
  const int b = bh >> 4, h = bh & 15;
  const unsigned lbase = __builtin_amdgcn_readfirstlane(w * 64 * 16);

  #pragma unroll
  for (int half = 0; half < 2; ++half) {
    const int qt = half ? (31 - p) : p;
    const long qrow0 = (long)b * 2048 + qt * 64;
    const int rowt = qt * 64 + w * 16 + l15;

    bf16x8 qf[6];
    {
      const short* qrow = (const short*)q + (qrow0 + w * 16 + l15) * 3072 + h * 192;
      #pragma unroll
      for (int kc = 0; kc < 6; ++kc)
        qf[kc] = *(const bf16x8*)(qrow + kc * 32 + l4 * 8);
    }
    {  // fused GPT-J RoPE on pe fragments (cols 128..191 = kc 4,5)
      float pos = (float)rowt;
      #pragma unroll
      for (int kc = 4; kc < 6; ++kc)
        #pragma unroll
        for (int pr = 0; pr < 4; ++pr) {
          int i = (kc - 4) * 16 + l4 * 4 + pr;
          float freq = __expf((float)i * -0.28782313662425572f);  // 10000^(-i/32)
          float sn, cs;
          sincosf(pos * freq, &sn, &cs);
          float x1 = bs2f(qf[kc][2 * pr]), x2 = bs2f(qf[kc][2 * pr + 1]);
          qf[kc][2 * pr]     = f2bs(x1 * cs - x2 * sn);
          qf[kc][2 * pr + 1] = f2bs(x2 * cs + x1 * sn);
        }
    }
    f32x4 o[8] = {};
    float mreg = -1e30f, ls = 0.f;
    const int nch = qt + 1;

    {  // prologue: stage K chunk 0
      const char* ksrc = (const char*)(Kf + (long)bh * 2048 * 192);
      #pragma unroll
      for (int jj = 0; jj < 6; ++jj)
        gload16(ksrc + (jj * 256 + tid) * 16, (char*)Ks + jj * 4096 + lbase);
    }
    __syncthreads();

    for (int c = 0; c < nch; ++c) {
      const int k0 = c * 64;
      {  // issue V(c) — drains at mid-barrier, hidden under QK+softmax
        #pragma unroll
        for (int jj = 0; jj < 4; ++jj) {
          int seg = jj * 256 + tid;
          const bf16* vsrc = Vt + ((long)bh * 128 + (seg >> 3)) * 2048 + k0 + (seg & 7) * 8;
          gload16(vsrc, (char*)Vs + jj * 4096 + lbase);
        }
      }
      __builtin_amdgcn_s_setprio(1);
      f32x4 s[4] = {};
      #pragma unroll
      for (int kc = 0; kc < 6; ++kc)
        #pragma unroll
        for (int kg = 0; kg < 4; ++kg) {
          int row = kg * 16 + l15;
          int slot = (kc * 4 + l4) ^ (l15 & 7);
          bf16x8 kb = *(const bf16x8*)&Ks[row * 192 + slot * 8];
          s[kg] = MFMA16(kb, qf[kc], s[kg]);   // SWAPPED: D[key][qrow]
        }
      __builtin_amdgcn_s_setprio(0);

      const bool diag = (c == qt);
      float pk[16];
      #pragma unroll
      for (int kg = 0; kg < 4; ++kg)
        #pragma unroll
        for (int r = 0; r < 4; ++r) {
          float v = s[kg][r];
          if (diag && (k0 + kg * 16 + l4 * 4 + r > rowt)) v = -1e30f;
          pk[kg * 4 + r] = v;
        }
      float cm = pk[0];
      #pragma unroll
      for (int i = 1; i < 16; ++i) cm = fmaxf(cm, pk[i]);
      cm = fmaxf(cm, __shfl_xor(cm, 16));
      cm = fmaxf(cm, __shfl_xor(cm, 32));
      cm *= SC2;  // scale once (monotone)
      if (__ballot(cm > mreg + 12.0f)) {  // defer-max rescale (wave-uniform)
        float mn = fmaxf(mreg, cm);
        float al = exp2f(mreg - mn);
        ls *= al;
        float af[4];
        #pragma unroll
        for (int r = 0; r < 4; ++r) af[r] = __shfl(al, l4 * 4 + r);
        #pragma unroll
        for (int f = 0; f < 8; ++f)
          #pragma unroll
          for (int r = 0; r < 4; ++r) o[f][r] *= af[r];
        mreg = mn;
      }
      float ps = 0.f;
      #pragma unroll
      for (int i = 0; i < 16; ++i) {
        pk[i] = exp2f(fmaf(pk[i], SC2, -mreg));
        ps += pk[i];
      }
      ps += __shfl_xor(ps, 16);
      ps += __shfl_xor(ps, 32);
      ls += ps;
      #pragma unroll
      for (int kg = 0; kg < 4; ++kg)
        #pragma unroll
        for (int pr = 0; pr < 2; ++pr) {
          int key2 = kg * 16 + l4 * 4 + pr * 2;
          int sl = (key2 >> 3) ^ (l15 & 7);
          unsigned lo = (unsigned short)f2bs(pk[kg * 4 + pr * 2]);
          unsigned hi = (unsigned short)f2bs(pk[kg * 4 + pr * 2 + 1]);
          *(unsigned*)&Ps[w][l15 * 64 + sl * 8 + (key2 & 7)] = lo | (hi << 16);
        }
      __syncthreads();  // mid-barrier: V(c) landed; Ks reads + Ps writes done

      if (c + 1 < nch) {  // issue K(c+1) — drains at end-barrier, under PV
        const char* ksrc = (const char*)(Kf + ((long)bh * 2048 + k0 + 64) * 192);
        #pragma unroll
        for (int jj = 0; jj < 6; ++jj)
          gload16(ksrc + (jj * 256 + tid) * 16, (char*)Ks + jj * 4096 + lbase);
      }

      __builtin_amdgcn_s_setprio(1);
      #pragma unroll
      for (int ks = 0; ks < 2; ++ks) {
        int psl = (ks * 4 + l4) ^ (l15 & 7);
        bf16x8 pa = *(const bf16x8*)&Ps[w][l15 * 64 + psl * 8];
        #pragma unroll
        for (int f = 0; f < 8; ++f) {
          int vrow = f * 16 + l15;
          int vsl = (ks * 4 + l4) ^ (l15 & 7);
          bf16x8 bv = *(const bf16x8*)&Vs[vrow * 64 + vsl * 8];
          o[f] = MFMA16(pa, bv, o[f]);
        }
      }
      __builtin_amdgcn_s_setprio(0);
      __syncthreads();  // end-barrier: K(c+1) landed; Vs reads done
    }

    #pragma unroll
    for (int r = 0; r < 4; ++r) {
      float lsr = __shfl(ls, l4 * 4 + r);
      float inv = 1.0f / lsr;
      long t = qrow0 + w * 16 + l4 * 4 + r;
      bf16* dst = attn + t * 2048 + h * 128;
      #pragma unroll
      for (int f = 0; f < 8; ++f)
        dst[f * 16 + l15] = __float2bfloat16(o[f][r] * inv);
    }
  }
}

// ---------------------------------------------------------------------------
extern "C" void kernel_launch(void* const* d_in, const int* in_sizes, int n_in,
                              void* d_out, int out_size, void* d_ws, size_t ws_size,
                              hipStream_t stream) {
  const float* hs_f   = (const float*)d_in[1];
  const float* Wqa_f  = (const float*)d_in[2];
  const float* qln_f  = (const float*)d_in[3];
  const float* Wqb_f  = (const float*)d_in[4];
  const float* Wkva_f = (const float*)d_in[5];
  const float* kvln_f = (const float*)d_in[6];
  const float* Wkvb_f = (const float*)d_in[7];
  const float* Wo_f   = (const float*)d_in[8];

  bf16* base = (bf16*)d_ws;
  bf16* hs_c  = base;                       // 8,388,608 (dead after gemmA) | q overlay
  bf16* wqaT  = base + 8388608;             // 3,145,728
  bf16* wkvaT = base + 11534336;            // 1,179,648 (ends 12,713,984)
  bf16* q     = base;                       // 12,582,912 overlay (gemm_dual+)
  bf16* ckq   = base + 12713984;            // 6,291,456 (dead after gemm_dual)
  bf16* qln_c = base + 19005440;            // 1536
  bf16* kvln_c= base + 19006976;            // 512   (ends 19,007,488)
  bf16* attnb = base + 12713984;            // 8,388,608 overlay over ckq+ln (attn+)
  bf16* wqbT  = base + 21102592;            // 4,718,592
  bf16* wkvbT = base + 25821184;            // 2,097,152
  bf16* woT   = base + 27918336;            // 4,194,304 (alive till gemmW)
  bf16* kvns  = base + 32112640;            // 2,621,440
  bf16* Kf    = base + 34734080;            // 12,582,912
  bf16* Vt    = base + 47316992;            // 8,388,608 (ends 55,705,600 = 111.4 MB)

  // 1) mega-prep: all conversions + all weight transposes
  prep_all<<<7841, 256, 0, stream>>>(hs_f, hs_c, qln_f, qln_c, kvln_f, kvln_c,
                                     Wqa_f, wqaT, Wkva_f, wkvaT,
                                     Wqb_f, wqbT, Wkvb_f, wkvbT, Wo_f, woT);
  // 2) fused: [ckq | kvns] = hs @ [Wqa | Wkva]  (N=2176, split at 1536)
  gemm_v4<false><<<dim3(17, 32), 256, 0, stream>>>(hs_c, wqaT, ckq, 2176, 2048,
                                                   2048, 2048, 1536, kvns, 1536);
  // 3) rmsnorms + fused k_pe rope -> Kf
  rms_pe_dual<<<8192, 256, 0, stream>>>(ckq, qln_c, kvns, kvln_c, Kf);
  // 4) merged: q = ckq@WqbT (over dead hs/wqaT/wkvaT) | {Kf, Vt} = kvns@WkvbT
  gemm_dual<<<1792, 256, 0, stream>>>(ckq, wqbT, q, kvns, wkvbT, Kf, Vt);
  // 5) attention (r18-proven v6 schedule)
  attn_v6<<<512, 256, 0, stream>>>(q, Kf, Vt, attnb);
  // 6) out = attn @ Wo (f32 output)
  gemm_v4<true><<<dim3(16, 32), 256, 0, stream>>>(attnb, woT, d_out, 2048, 2048,
                                                  2048, 2048, 2048, nullptr, 0);
}